// Round 1
// baseline (152.772 us; speedup 1.0000x reference)
//
#include <hip/hip_runtime.h>
#include <math.h>

#define NUM_ENT 14541
#define NUM_REL2 474
#define EMBED_D 200
#define BATCH 256
#define GAMMA 9.0f

#define TILE 64      // output tile is TILE x TILE (b x n)
#define CHUNK 8      // D-chunk streamed through LDS for entity rows
#define EPAD 12      // padded row stride for ent chunk (48B, 16B-aligned, <=2-way banks)

// 256 threads: tx = tid&15 (n dim), ty = tid>>4 (b dim); 4x4 micro-tile each.
__global__ __launch_bounds__(256, 2)
void transe_score_kernel(const float* __restrict__ ent,
                         const float* __restrict__ relE,
                         const int*   __restrict__ sub_idx,
                         const int*   __restrict__ rel_idx,
                         float*       __restrict__ out)
{
    __shared__ float obj_s[TILE][EMBED_D];   // 51200 B: obj rows for this b-tile, full D
    __shared__ float ent_c[TILE][EPAD];      // 3072 B: entity rows, current D-chunk
    __shared__ int   s_sub[TILE];
    __shared__ int   s_rel[TILE];

    const int tid   = threadIdx.x;
    const int nbase = blockIdx.x * TILE;
    const int bbase = blockIdx.y * TILE;

    // stage gather indices
    if (tid < TILE)            s_sub[tid]        = sub_idx[bbase + tid];
    else if (tid < 2 * TILE)   s_rel[tid - TILE] = rel_idx[bbase + tid - TILE];
    __syncthreads();

    // build obj tile: obj_s[r][d] = ent[sub[b]][d] + relE[rel[b]][d], float2 granularity
    for (int idx = tid; idx < TILE * (EMBED_D / 2); idx += 256) {
        const int r = idx / (EMBED_D / 2);
        const int d = (idx - r * (EMBED_D / 2)) * 2;
        const float* ep = ent  + (size_t)s_sub[r] * EMBED_D + d;
        const float* rp = relE + (size_t)s_rel[r] * EMBED_D + d;
        obj_s[r][d]     = ep[0] + rp[0];
        obj_s[r][d + 1] = ep[1] + rp[1];
    }

    const int tx = tid & 15;
    const int ty = tid >> 4;

    float acc[4][4];
#pragma unroll
    for (int i = 0; i < 4; ++i)
#pragma unroll
        for (int j = 0; j < 4; ++j) acc[i][j] = 0.0f;

    // entity-chunk staging indices: 4 threads per row, float2 each
    const int er = tid >> 2;             // 0..63
    const int ec = (tid & 3) * 2;        // 0,2,4,6
    int eg = nbase + er;
    if (eg >= NUM_ENT) eg = NUM_ENT - 1; // clamp (dup loads; stores guarded later)
    const float* egp = ent + (size_t)eg * EMBED_D + ec;

#pragma unroll 1
    for (int c = 0; c < EMBED_D / CHUNK; ++c) {
        // stage ent chunk [64][8]
        const float2 ev = *(const float2*)(egp + c * CHUNK);
        ent_c[er][ec]     = ev.x;
        ent_c[er][ec + 1] = ev.y;
        __syncthreads();   // chunk (and on c==0, obj tile) visible

        // load this thread's 4 entity rows for the chunk
        float e[4][8];
#pragma unroll
        for (int j = 0; j < 4; ++j) {
            const float* p = &ent_c[tx + 16 * j][0];
            const float4 a = *(const float4*)p;
            const float4 b = *(const float4*)(p + 4);
            e[j][0] = a.x; e[j][1] = a.y; e[j][2] = a.z; e[j][3] = a.w;
            e[j][4] = b.x; e[j][5] = b.y; e[j][6] = b.z; e[j][7] = b.w;
        }

#pragma unroll
        for (int i = 0; i < 4; ++i) {
            const float* p = &obj_s[ty + 16 * i][c * CHUNK];
            const float4 a = *(const float4*)p;
            const float4 b = *(const float4*)(p + 4);
            float o[8];
            o[0] = a.x; o[1] = a.y; o[2] = a.z; o[3] = a.w;
            o[4] = b.x; o[5] = b.y; o[6] = b.z; o[7] = b.w;
#pragma unroll
            for (int j = 0; j < 4; ++j) {
#pragma unroll
                for (int d = 0; d < 8; ++d) {
                    acc[i][j] += fabsf(o[d] - e[j][d]);
                }
            }
        }
        __syncthreads();   // before next chunk overwrites ent_c
    }

    // epilogue: sigmoid(GAMMA - dist), coalesced along n
#pragma unroll
    for (int i = 0; i < 4; ++i) {
        const int b_g = bbase + ty + 16 * i;
#pragma unroll
        for (int j = 0; j < 4; ++j) {
            const int n_g = nbase + tx + 16 * j;
            if (n_g < NUM_ENT) {
                const float s = 1.0f / (1.0f + expf(acc[i][j] - GAMMA));
                out[(size_t)b_g * NUM_ENT + n_g] = s;
            }
        }
    }
}

extern "C" void kernel_launch(void* const* d_in, const int* in_sizes, int n_in,
                              void* d_out, int out_size, void* d_ws, size_t ws_size,
                              hipStream_t stream) {
    const float* ent  = (const float*)d_in[0];
    const float* relE = (const float*)d_in[1];
    const int*   sub  = (const int*)d_in[2];
    const int*   rel  = (const int*)d_in[3];
    // d_in[4] (neg_ents) unused by the reference computation
    float* out = (float*)d_out;

    const int n_tiles = (NUM_ENT + TILE - 1) / TILE;   // 228
    const int b_tiles = BATCH / TILE;                  // 4
    dim3 grid(n_tiles, b_tiles);
    transe_score_kernel<<<grid, 256, 0, stream>>>(ent, relE, sub, rel, out);
}

// Round 2
// 118.549 us; speedup vs baseline: 1.2887x; 1.2887x over previous
//
#include <hip/hip_runtime.h>
#include <math.h>

#define NUM_ENT 14541
#define NUM_REL2 474
#define EMBED_D 200
#define BATCH 256
#define GAMMA 9.0f

#define TILE 64        // output tile is TILE(b) x TILE(n)
#define CHUNK 40       // D-chunk streamed through LDS (5 chunks of 200)
#define STRIDE 44      // padded row stride: 44 mod 32 = 12 -> max 2-way bank alias (free)
#define NF4 (CHUNK / 4)       // 10 float4 per row-chunk
#define NITEMS (TILE * NF4)   // 640 float4 items per tile side

// 256 threads: tx = tid&15 (n dim), ty = tid>>4 (b dim); 4x4 micro-tile each.
__global__ __launch_bounds__(256, 4)
void transe_score_kernel(const float* __restrict__ ent,
                         const float* __restrict__ relE,
                         const int*   __restrict__ sub_idx,
                         const int*   __restrict__ rel_idx,
                         float*       __restrict__ out)
{
    __shared__ float obj_s[TILE][STRIDE];   // 11264 B
    __shared__ float ent_s[TILE][STRIDE];   // 11264 B
    __shared__ int   s_sub[TILE];
    __shared__ int   s_rel[TILE];

    const int tid   = threadIdx.x;
    const int nbase = blockIdx.x * TILE;
    const int bbase = blockIdx.y * TILE;

    if (tid < TILE)          s_sub[tid]        = sub_idx[bbase + tid];
    else if (tid < 2 * TILE) s_rel[tid - TILE] = rel_idx[bbase + tid - TILE];
    __syncthreads();

    const int tx = tid & 15;
    const int ty = tid >> 4;

    float acc[4][4];
#pragma unroll
    for (int i = 0; i < 4; ++i)
#pragma unroll
        for (int j = 0; j < 4; ++j) acc[i][j] = 0.0f;

#pragma unroll 1
    for (int c = 0; c < EMBED_D / CHUNK; ++c) {
        const int dbase = c * CHUNK;

        // stage both tiles' current D-chunk: 640 float4 per side, 256 threads
        for (int it = tid; it < NITEMS; it += 256) {
            const int row = it / NF4;
            const int col = (it - row * NF4) * 4;

            int eg = nbase + row;
            if (eg >= NUM_ENT) eg = NUM_ENT - 1;   // clamp; stores guarded in epilogue
            const float4 ev = *(const float4*)(ent + (size_t)eg * EMBED_D + dbase + col);
            *(float4*)&ent_s[row][col] = ev;

            const float4 av = *(const float4*)(ent  + (size_t)s_sub[row] * EMBED_D + dbase + col);
            const float4 rv = *(const float4*)(relE + (size_t)s_rel[row] * EMBED_D + dbase + col);
            float4 ov;
            ov.x = av.x + rv.x; ov.y = av.y + rv.y;
            ov.z = av.z + rv.z; ov.w = av.w + rv.w;
            *(float4*)&obj_s[row][col] = ov;
        }
        __syncthreads();

        // compute: 5 sub-steps of 8 d's, no barriers inside
#pragma unroll
        for (int s = 0; s < CHUNK / 8; ++s) {
            float e[4][8];
#pragma unroll
            for (int j = 0; j < 4; ++j) {
                const float* p = &ent_s[tx + 16 * j][s * 8];
                const float4 a = *(const float4*)p;
                const float4 b = *(const float4*)(p + 4);
                e[j][0] = a.x; e[j][1] = a.y; e[j][2] = a.z; e[j][3] = a.w;
                e[j][4] = b.x; e[j][5] = b.y; e[j][6] = b.z; e[j][7] = b.w;
            }
#pragma unroll
            for (int i = 0; i < 4; ++i) {
                const float* p = &obj_s[ty + 16 * i][s * 8];
                const float4 a = *(const float4*)p;
                const float4 b = *(const float4*)(p + 4);
                float o[8];
                o[0] = a.x; o[1] = a.y; o[2] = a.z; o[3] = a.w;
                o[4] = b.x; o[5] = b.y; o[6] = b.z; o[7] = b.w;
#pragma unroll
                for (int j = 0; j < 4; ++j) {
#pragma unroll
                    for (int d = 0; d < 8; ++d) {
                        acc[i][j] += fabsf(o[d] - e[j][d]);
                    }
                }
            }
        }
        __syncthreads();
    }

    // epilogue: sigmoid(GAMMA - dist)
#pragma unroll
    for (int i = 0; i < 4; ++i) {
        const int b_g = bbase + ty + 16 * i;
#pragma unroll
        for (int j = 0; j < 4; ++j) {
            const int n_g = nbase + tx + 16 * j;
            if (n_g < NUM_ENT) {
                const float s = 1.0f / (1.0f + expf(acc[i][j] - GAMMA));
                out[(size_t)b_g * NUM_ENT + n_g] = s;
            }
        }
    }
}

extern "C" void kernel_launch(void* const* d_in, const int* in_sizes, int n_in,
                              void* d_out, int out_size, void* d_ws, size_t ws_size,
                              hipStream_t stream) {
    const float* ent  = (const float*)d_in[0];
    const float* relE = (const float*)d_in[1];
    const int*   sub  = (const int*)d_in[2];
    const int*   rel  = (const int*)d_in[3];
    float* out = (float*)d_out;

    const int n_tiles = (NUM_ENT + TILE - 1) / TILE;   // 228
    const int b_tiles = BATCH / TILE;                  // 4
    dim3 grid(n_tiles, b_tiles);
    transe_score_kernel<<<grid, 256, 0, stream>>>(ent, relE, sub, rel, out);
}